// Round 1
// baseline (15661.942 us; speedup 1.0000x reference)
//
#include <hip/hip_runtime.h>
#include <hip/hip_bf16.h>
#include <stdint.h>

// LSTM (T=1024, B=64, D=512, H=512) on gfx950.
// Phase 1: X[t,b,n] = inputs @ Wx (packed, bf16 MFMA), n = h*4 + gate.
// Phase 2: persistent 64-WG kernel, 1024 steps, W_h fragments in registers,
//          custom device-scope barrier per step.

typedef float    f32x4  __attribute__((ext_vector_type(4)));
typedef short    s16x8  __attribute__((ext_vector_type(8)));
typedef unsigned short u16;
typedef u16      u16x4  __attribute__((ext_vector_type(4)));

#define TT 1024
#define BB 64
#define DD 512
#define HH 512
#define NG 2048   // 4*HH packed gate columns: n = h*4 + g, g in {i,f,o,c}

__device__ __forceinline__ u16 f2bf(float f) {
  __hip_bfloat16 h = __float2bfloat16(f);
  union { __hip_bfloat16 b; u16 u; } v; v.b = h; return v.u;
}
__device__ __forceinline__ float bf2f(u16 u) {
  union { unsigned int i; float f; } v; v.i = ((unsigned int)u) << 16; return v.f;
}

__device__ __forceinline__ void gload_lds16(const u16* g, u16* l) {
  __builtin_amdgcn_global_load_lds(
      (const __attribute__((address_space(1))) unsigned int*)g,
      (__attribute__((address_space(3))) unsigned int*)l, 16, 0, 0);
}

// ---------------- setup: cast inputs fp32 -> bf16 ----------------
__global__ void k_cast(const float* __restrict__ in, u16* __restrict__ out, long n) {
  long i = ((long)blockIdx.x * blockDim.x + threadIdx.x) * 4;
  if (i >= n) return;
  const float4 v = *(const float4*)(in + i);
  u16x4 o; o.x = f2bf(v.x); o.y = f2bf(v.y); o.z = f2bf(v.z); o.w = f2bf(v.w);
  *(u16x4*)(out + i) = o;
}

// ---------------- setup: pack weights transposed + gate-interleaved ----------------
// WxT[n][k], WhT[n][k] bf16 with n = h*4+g; biasp[n] fp32.
__global__ void k_pack(const float* __restrict__ Wxi, const float* __restrict__ Whi, const float* __restrict__ bi,
                       const float* __restrict__ Wxf, const float* __restrict__ Whf, const float* __restrict__ bfi,
                       const float* __restrict__ Wxo, const float* __restrict__ Who, const float* __restrict__ bo,
                       const float* __restrict__ Wxc, const float* __restrict__ Whc, const float* __restrict__ bc,
                       u16* __restrict__ WxT, u16* __restrict__ WhT, float* __restrict__ biasp)
{
  const int k = blockIdx.x;  // 0..511
  const float* Wx[4] = {Wxi, Wxf, Wxo, Wxc};
  const float* Wh[4] = {Whi, Whf, Who, Whc};
  for (int h = threadIdx.x; h < HH; h += blockDim.x) {
#pragma unroll
    for (int g = 0; g < 4; ++g) {
      const long n = h * 4 + g;
      WxT[n * DD + k] = f2bf(Wx[g][(long)k * HH + h]);
      WhT[n * HH + k] = f2bf(Wh[g][(long)k * HH + h]);
    }
  }
  if (k == 0) {
    const float* bp[4] = {bi, bfi, bo, bc};
    for (int n = threadIdx.x; n < NG; n += blockDim.x)
      biasp[n] = bp[n & 3][n >> 2];
  }
}

// ---------------- phase 1: X = A(bf16) @ WxT^T + bias, store bf16 ----------------
// A: [rows][512] bf16 row-major.  BT: [2048][512] bf16 (transposed B).
// X: [rows][2048] bf16.  Grid: (NG/128, rows/128), 256 threads.
__global__ __launch_bounds__(256) void k_gemm_x(
    const u16* __restrict__ A, const u16* __restrict__ BT,
    const float* __restrict__ biasp, u16* __restrict__ X)
{
  __shared__ __align__(16) u16 As[128 * 64];
  __shared__ __align__(16) u16 Bs[128 * 64];
  const int tid = threadIdx.x;
  const int l = tid & 63;
  const int w = tid >> 6;
  const int wr = w >> 1, wc = w & 1;
  const long brow = (long)blockIdx.y * 128;
  const int  bcol = blockIdx.x * 128;
  const int  lr = l >> 3, lc = l & 7;     // staging: 8 lanes/row, 16B each
  const int  cl = l & 15, rg = l >> 4;

  f32x4 acc[4][4];
#pragma unroll
  for (int m = 0; m < 4; ++m)
#pragma unroll
    for (int n = 0; n < 4; ++n) acc[m][n] = (f32x4){0.f, 0.f, 0.f, 0.f};

  for (int k0 = 0; k0 < DD; k0 += 64) {
#pragma unroll
    for (int j = 0; j < 4; ++j) {
      const int sub = w * 4 + j;          // 0..15, 8 rows per call
      gload_lds16(A  + (brow + sub * 8 + lr) * DD + k0 + lc * 8, &As[sub * 512]);
      gload_lds16(BT + ((long)(bcol + sub * 8 + lr)) * DD + k0 + lc * 8, &Bs[sub * 512]);
    }
    __syncthreads();
#pragma unroll
    for (int kk = 0; kk < 2; ++kk) {
      s16x8 af[4], bfr[4];
#pragma unroll
      for (int m = 0; m < 4; ++m)
        af[m] = *(const s16x8*)&As[(wr * 64 + m * 16 + cl) * 64 + kk * 32 + rg * 8];
#pragma unroll
      for (int n = 0; n < 4; ++n)
        bfr[n] = *(const s16x8*)&Bs[(wc * 64 + n * 16 + cl) * 64 + kk * 32 + rg * 8];
#pragma unroll
      for (int m = 0; m < 4; ++m)
#pragma unroll
        for (int n = 0; n < 4; ++n)
          acc[m][n] = __builtin_amdgcn_mfma_f32_16x16x32_bf16(af[m], bfr[n], acc[m][n], 0, 0, 0);
    }
    __syncthreads();
  }
#pragma unroll
  for (int n = 0; n < 4; ++n) {
    const int col = bcol + wc * 64 + n * 16 + cl;
    const float bv = biasp[col];
#pragma unroll
    for (int m = 0; m < 4; ++m)
#pragma unroll
      for (int j = 0; j < 4; ++j) {
        const long row = brow + wr * 64 + m * 16 + rg * 4 + j;
        X[row * NG + col] = f2bf(acc[m][n][j] + bv);
      }
  }
}

// ---------------- phase 2: persistent recurrent kernel ----------------
// 64 WGs x 256 threads. WG w owns H columns [8w, 8w+8) (gate cols [32w,32w+32)).
// B-fragments of WhT held in registers. One device barrier per step.
__global__ __launch_bounds__(256) void k_lstm(
    const u16* __restrict__ X, const u16* __restrict__ WhT,
    u16* __restrict__ Hbuf0, u16* __restrict__ Hbuf1,
    float* __restrict__ Cst, float* __restrict__ dout,
    float* __restrict__ doutH, float* __restrict__ doutC,
    unsigned int* __restrict__ cnt, int t0, int t1)
{
  __shared__ __align__(16) float pre[64][40];   // 40 > 32 pads banks + keeps 16B align
  __shared__ __align__(16) float Cs[64][8];
  const int tid = threadIdx.x;
  const int l = tid & 63, v = tid >> 6;         // wave v owns batch rows [16v,16v+16)
  const int w = blockIdx.x;                     // 0..63
  const int cl = l & 15, rg = l >> 4;

  // constant B fragments: WhT cols 32w..32w+32
  s16x8 bfr[2][16];
#pragma unroll
  for (int nt = 0; nt < 2; ++nt)
#pragma unroll
    for (int ks = 0; ks < 16; ++ks)
      bfr[nt][ks] = *(const s16x8*)&WhT[(long)(w * 32 + nt * 16 + cl) * HH + ks * 32 + rg * 8];

  // pointwise ownership: thread -> batch row r, h-pair (h0, h0+1)
  const int r = tid >> 2;
  const int h0 = (tid & 3) * 2;

  if (t0 == 0) {
    Cs[r][h0] = 0.f; Cs[r][h0 + 1] = 0.f;
  } else {
    Cs[r][h0]     = Cst[r * HH + w * 8 + h0];
    Cs[r][h0 + 1] = Cst[r * HH + w * 8 + h0 + 1];
  }

  const u16* Hc = Hbuf0;
  u16* Hn = Hbuf1;
  __syncthreads();

  for (int t = t0; t < t1; ++t) {
    const int s = t - t0;
    // X for this step: 8 contiguous bf16 = the 4 gates of h0 and h0+1
    s16x8 xv = *(const s16x8*)&X[((long)s * BB + r) * NG + w * 32 + h0 * 4];

    f32x4 acc0 = (f32x4){0.f,0.f,0.f,0.f}, acc1 = (f32x4){0.f,0.f,0.f,0.f};
    if (t > 0) {
#pragma unroll
      for (int ks = 0; ks < 16; ++ks) {
        s16x8 af = *(const s16x8*)&Hc[(v * 16 + cl) * HH + ks * 32 + rg * 8];
        acc0 = __builtin_amdgcn_mfma_f32_16x16x32_bf16(af, bfr[0][ks], acc0, 0, 0, 0);
        acc1 = __builtin_amdgcn_mfma_f32_16x16x32_bf16(af, bfr[1][ks], acc1, 0, 0, 0);
      }
    }
#pragma unroll
    for (int j = 0; j < 4; ++j) {
      pre[v * 16 + rg * 4 + j][cl]      = acc0[j];
      pre[v * 16 + rg * 4 + j][16 + cl] = acc1[j];
    }
    __syncthreads();

    // pointwise: gates -> C,H update
#pragma unroll
    for (int q = 0; q < 2; ++q) {
      const int h = h0 + q;
      f32x4 p = *(const f32x4*)&pre[r][h * 4];
      const float pi = p[0] + bf2f((u16)xv[q * 4 + 0]);
      const float pf = p[1] + bf2f((u16)xv[q * 4 + 1]);
      const float po = p[2] + bf2f((u16)xv[q * 4 + 2]);
      const float pc = p[3] + bf2f((u16)xv[q * 4 + 3]);
      const float ig = 1.f / (1.f + __expf(-pi));
      const float fg = 1.f / (1.f + __expf(-pf));
      const float og = 1.f / (1.f + __expf(-po));
      const float ct = tanhf(pc);
      const float c  = fg * Cs[r][h] + ig * ct;
      Cs[r][h] = c;
      const float hv = og * tanhf(c);
      const int hg = w * 8 + h;
      Hn[r * HH + hg] = f2bf(hv);
      dout[((long)t * BB + r) * HH + hg] = hv;
      if (t == TT - 1) { doutH[r * HH + hg] = hv; doutC[r * HH + hg] = c; }
    }

    // device barrier: release stores, arrive, spin, acquire
    __threadfence();
    __syncthreads();
    if (tid == 0) {
      __hip_atomic_fetch_add(cnt, 1u, __ATOMIC_RELAXED, __HIP_MEMORY_SCOPE_AGENT);
      const unsigned int tgt = 64u * (unsigned int)(s + 1);
      while (__hip_atomic_load(cnt, __ATOMIC_RELAXED, __HIP_MEMORY_SCOPE_AGENT) < tgt)
        __builtin_amdgcn_s_sleep(1);
    }
    __syncthreads();
    __threadfence();

    const u16* tc = Hc; Hc = Hn; Hn = (u16*)tc;
  }

  // persist C for the next chunk
  Cst[r * HH + w * 8 + h0]     = Cs[r][h0];
  Cst[r * HH + w * 8 + h0 + 1] = Cs[r][h0 + 1];
}

// ---------------- host ----------------
extern "C" void kernel_launch(void* const* d_in, const int* in_sizes, int n_in,
                              void* d_out, int out_size, void* d_ws, size_t ws_size,
                              hipStream_t stream)
{
  const float* inputs = (const float*)d_in[0];
  const float* W_xi = (const float*)d_in[1];
  const float* W_hi = (const float*)d_in[2];
  const float* b_i  = (const float*)d_in[3];
  const float* W_xf = (const float*)d_in[4];
  const float* W_hf = (const float*)d_in[5];
  const float* b_f  = (const float*)d_in[6];
  const float* W_xo = (const float*)d_in[7];
  const float* W_ho = (const float*)d_in[8];
  const float* b_o  = (const float*)d_in[9];
  const float* W_xc = (const float*)d_in[10];
  const float* W_hc = (const float*)d_in[11];
  const float* b_c  = (const float*)d_in[12];
  float* out = (float*)d_out;
  char* ws = (char*)d_ws;

  size_t off = 0;
  auto walloc = [&](size_t sz) { size_t o = off; off = (off + sz + 255) & ~(size_t)255; return o; };
  const size_t o_inbf = walloc((size_t)TT * BB * DD * 2);   // 64 MB
  const size_t o_WxT  = walloc((size_t)NG * DD * 2);        // 2 MB
  const size_t o_WhT  = walloc((size_t)NG * HH * 2);        // 2 MB
  const size_t o_bias = walloc((size_t)NG * 4);
  const size_t o_H0   = walloc((size_t)BB * HH * 2);
  const size_t o_H1   = walloc((size_t)BB * HH * 2);
  const size_t o_C    = walloc((size_t)BB * HH * 4);
  const size_t o_cnt  = walloc(256);
  const size_t o_X    = off;

  const size_t bytes_per_step = (size_t)BB * NG * 2;        // 256 KB
  long spc = (ws_size > o_X) ? (long)((ws_size - o_X) / bytes_per_step) : 0;
  if (spc > TT) spc = TT;
  spc &= ~1L;               // keep even so GEMM M-tiles (128 rows = 2 steps) divide
  if (spc < 2) spc = 2;

  u16*   inbf  = (u16*)(ws + o_inbf);
  u16*   WxT   = (u16*)(ws + o_WxT);
  u16*   WhT   = (u16*)(ws + o_WhT);
  float* biasp = (float*)(ws + o_bias);
  u16*   Xbuf  = (u16*)(ws + o_X);
  float* Cst   = (float*)(ws + o_C);

  k_cast<<<dim3((TT * BB * DD) / 1024), dim3(256), 0, stream>>>(inputs, inbf, (long)TT * BB * DD);
  k_pack<<<dim3(DD), dim3(256), 0, stream>>>(W_xi, W_hi, b_i, W_xf, W_hf, b_f,
                                             W_xo, W_ho, b_o, W_xc, W_hc, b_c,
                                             WxT, WhT, biasp);

  float* doutH = out + (size_t)TT * BB * HH;
  float* doutC = doutH + (size_t)BB * HH;

  for (int t0 = 0; t0 < TT; t0 += (int)spc) {
    int t1 = t0 + (int)spc; if (t1 > TT) t1 = TT;
    const int rows = (t1 - t0) * BB;
    k_gemm_x<<<dim3(NG / 128, rows / 128), dim3(256), 0, stream>>>(
        inbf + (size_t)t0 * BB * DD, WxT, biasp, Xbuf);
    hipMemsetAsync(ws + o_cnt, 0, 256, stream);
    u16* h0p = (u16*)(ws + ((t0 & 1) ? o_H1 : o_H0));
    u16* h1p = (u16*)(ws + ((t0 & 1) ? o_H0 : o_H1));
    k_lstm<<<dim3(64), dim3(256), 0, stream>>>(
        Xbuf, WhT, h0p, h1p, Cst, out, doutH, doutC,
        (unsigned int*)(ws + o_cnt), t0, t1);
  }
}

// Round 3
// 6453.452 us; speedup vs baseline: 2.4269x; 2.4269x over previous
//
#include <hip/hip_runtime.h>
#include <hip/hip_bf16.h>
#include <stdint.h>

// LSTM (T=1024, B=64, D=512, H=512) on gfx950.
// Phase 1: X[t,b,n] = inputs @ Wx (packed, bf16 MFMA), n = h*4 + gate.
// Phase 2: 32 persistent WGs across the whole device. H exchanged at DEVICE
//   scope (sc1 -> MALL / Infinity Cache, placement-independent). Per-WG
//   padded arrive-flags (agent-scope atomics) + single-phase all-observe
//   barrier. H history buffer kills WAR hazards and stale-line reuse.
//   No threadfence / wbl2 anywhere in the hot loop.

typedef float    f32x4  __attribute__((ext_vector_type(4)));
typedef short    s16x8  __attribute__((ext_vector_type(8)));
typedef unsigned short u16;
typedef u16      u16x4  __attribute__((ext_vector_type(4)));
typedef unsigned int u32;

#define TT 1024
#define BB 64
#define DD 512
#define HH 512
#define NG 2048   // 4*HH packed gate columns: n = h*4 + g, g in {i,f,o,c}
#define NPART 32  // participant WGs

__device__ __forceinline__ u16 f2bf(float f) {
  __hip_bfloat16 h = __float2bfloat16(f);
  union { __hip_bfloat16 b; u16 u; } v; v.b = h; return v.u;
}
__device__ __forceinline__ float bf2f(u16 u) {
  union { unsigned int i; float f; } v; v.i = ((unsigned int)u) << 16; return v.f;
}

__device__ __forceinline__ void gload_lds16(const u16* g, u16* l) {
  __builtin_amdgcn_global_load_lds(
      (const __attribute__((address_space(1))) unsigned int*)g,
      (__attribute__((address_space(3))) unsigned int*)l, 16, 0, 0);
}

// device-scope (MALL) 16B load / 4B store: sc1 = device scope on gfx950
__device__ __forceinline__ s16x8 ld_b128_dev(const u16* p) {
  s16x8 v;
  asm volatile("global_load_dwordx4 %0, %1, off sc1" : "=v"(v) : "v"(p) : "memory");
  return v;
}
__device__ __forceinline__ void st_b32_dev(u16* p, u32 v) {
  asm volatile("global_store_dword %0, %1, off sc1" :: "v"(p), "v"(v) : "memory");
}

// ---------------- setup: cast inputs fp32 -> bf16 ----------------
__global__ void k_cast(const float* __restrict__ in, u16* __restrict__ out, long n) {
  long i = ((long)blockIdx.x * blockDim.x + threadIdx.x) * 4;
  if (i >= n) return;
  const float4 v = *(const float4*)(in + i);
  u16x4 o; o.x = f2bf(v.x); o.y = f2bf(v.y); o.z = f2bf(v.z); o.w = f2bf(v.w);
  *(u16x4*)(out + i) = o;
}

// ---------------- setup: pack weights transposed + gate-interleaved ----------------
__global__ void k_pack(const float* __restrict__ Wxi, const float* __restrict__ Whi, const float* __restrict__ bi,
                       const float* __restrict__ Wxf, const float* __restrict__ Whf, const float* __restrict__ bfi,
                       const float* __restrict__ Wxo, const float* __restrict__ Who, const float* __restrict__ bo,
                       const float* __restrict__ Wxc, const float* __restrict__ Whc, const float* __restrict__ bc,
                       u16* __restrict__ WxT, u16* __restrict__ WhT, float* __restrict__ biasp)
{
  const int k = blockIdx.x;  // 0..511
  const float* Wx[4] = {Wxi, Wxf, Wxo, Wxc};
  const float* Wh[4] = {Whi, Whf, Who, Whc};
  for (int h = threadIdx.x; h < HH; h += blockDim.x) {
#pragma unroll
    for (int g = 0; g < 4; ++g) {
      const long n = h * 4 + g;
      WxT[n * DD + k] = f2bf(Wx[g][(long)k * HH + h]);
      WhT[n * HH + k] = f2bf(Wh[g][(long)k * HH + h]);
    }
  }
  if (k == 0) {
    const float* bp[4] = {bi, bfi, bo, bc};
    for (int n = threadIdx.x; n < NG; n += blockDim.x)
      biasp[n] = bp[n & 3][n >> 2];
  }
}

// ---------------- phase 1: X = A(bf16) @ WxT^T + bias, store bf16 ----------------
__global__ __launch_bounds__(256) void k_gemm_x(
    const u16* __restrict__ A, const u16* __restrict__ BT,
    const float* __restrict__ biasp, u16* __restrict__ X)
{
  __shared__ __align__(16) u16 As[128 * 64];
  __shared__ __align__(16) u16 Bs[128 * 64];
  const int tid = threadIdx.x;
  const int l = tid & 63;
  const int w = tid >> 6;
  const int wr = w >> 1, wc = w & 1;
  const long brow = (long)blockIdx.y * 128;
  const int  bcol = blockIdx.x * 128;
  const int  lr = l >> 3, lc = l & 7;
  const int  cl = l & 15, rg = l >> 4;

  f32x4 acc[4][4];
#pragma unroll
  for (int m = 0; m < 4; ++m)
#pragma unroll
    for (int n = 0; n < 4; ++n) acc[m][n] = (f32x4){0.f, 0.f, 0.f, 0.f};

  for (int k0 = 0; k0 < DD; k0 += 64) {
#pragma unroll
    for (int j = 0; j < 4; ++j) {
      const int sub = w * 4 + j;
      gload_lds16(A  + (brow + sub * 8 + lr) * DD + k0 + lc * 8, &As[sub * 512]);
      gload_lds16(BT + ((long)(bcol + sub * 8 + lr)) * DD + k0 + lc * 8, &Bs[sub * 512]);
    }
    __syncthreads();
#pragma unroll
    for (int kk = 0; kk < 2; ++kk) {
      s16x8 af[4], bfr[4];
#pragma unroll
      for (int m = 0; m < 4; ++m)
        af[m] = *(const s16x8*)&As[(wr * 64 + m * 16 + cl) * 64 + kk * 32 + rg * 8];
#pragma unroll
      for (int n = 0; n < 4; ++n)
        bfr[n] = *(const s16x8*)&Bs[(wc * 64 + n * 16 + cl) * 64 + kk * 32 + rg * 8];
#pragma unroll
      for (int m = 0; m < 4; ++m)
#pragma unroll
        for (int n = 0; n < 4; ++n)
          acc[m][n] = __builtin_amdgcn_mfma_f32_16x16x32_bf16(af[m], bfr[n], acc[m][n], 0, 0, 0);
    }
    __syncthreads();
  }
#pragma unroll
  for (int n = 0; n < 4; ++n) {
    const int col = bcol + wc * 64 + n * 16 + cl;
    const float bv = biasp[col];
#pragma unroll
    for (int m = 0; m < 4; ++m)
#pragma unroll
      for (int j = 0; j < 4; ++j) {
        const long row = brow + wr * 64 + m * 16 + rg * 4 + j;
        X[row * NG + col] = f2bf(acc[m][n][j] + bv);
      }
  }
}

// ---------------- phase 2: device-wide recurrent kernel, 32 WGs ----------------
// role = blockIdx.x: bi = role>>3 (batch rows [16bi,16bi+16)),
//                    nj = role&7  (h cols [64nj,64nj+64)).
__global__ __launch_bounds__(512, 2) void k_lstm(
    const u16* __restrict__ X, const u16* __restrict__ WhT,
    u16* __restrict__ Hh, float* __restrict__ Cst,
    float* __restrict__ dout, float* __restrict__ doutH, float* __restrict__ doutC,
    u32* __restrict__ flags, int t0, int t1)
{
  __shared__ __align__(16) float pre[16][260];
  const int tid = threadIdx.x;
  const int role = blockIdx.x;
  const int bi = role >> 3;
  const int nj = role & 7;
  const int l  = tid & 63, wv = tid >> 6;
  const int cl = l & 15, rg = l >> 4;
  const int gbase = nj * 256 + wv * 32;   // this wave's gate-col base

  // constant B fragments (registers, loaded once)
  s16x8 bfr[2][16];
#pragma unroll
  for (int nt = 0; nt < 2; ++nt)
#pragma unroll
    for (int ks = 0; ks < 16; ++ks)
      bfr[nt][ks] = *(const s16x8*)&WhT[(long)(gbase + nt * 16 + cl) * HH + ks * 32 + rg * 8];

  // pointwise ownership
  const int r    = tid >> 5;           // 0..15
  const int hp   = tid & 31;           // 0..31
  const int rowg = bi * 16 + r;
  const int hg0  = nj * 64 + 2 * hp;

  float c0, c1;
  if (t0 == 0) { c0 = 0.f; c1 = 0.f; }
  else { c0 = Cst[rowg * HH + hg0]; c1 = Cst[rowg * HH + hg0 + 1]; }

  for (int t = t0; t < t1; ++t) {
    const int s = t - t0;
    // X prefetch (independent of the recurrence; issued before the poll)
    s16x8 xv = *(const s16x8*)&X[((long)s * BB + rowg) * NG + nj * 256 + hp * 8];

    if (t > t0) {                       // all-observe: every flag >= t
      if (wv == 0) {
        const u32 tgt = (u32)t;
        u32 vv; unsigned long long b;
        do {
          vv = (l < NPART)
             ? __hip_atomic_load(&flags[l * 32], __ATOMIC_RELAXED, __HIP_MEMORY_SCOPE_AGENT)
             : tgt;
          b = __ballot(vv >= tgt);
        } while (b != ~0ULL);
      }
      __syncthreads();
    }

    f32x4 acc0 = (f32x4){0.f,0.f,0.f,0.f}, acc1 = (f32x4){0.f,0.f,0.f,0.f};
    if (t > 0) {
      const u16* Hp = Hh + (long)(t - 1) * BB * HH;
      s16x8 af[16];
#pragma unroll
      for (int ks = 0; ks < 16; ++ks)
        af[ks] = ld_b128_dev(&Hp[(bi * 16 + cl) * HH + ks * 32 + rg * 8]);
      asm volatile("s_waitcnt vmcnt(0)" ::: "memory");
      __builtin_amdgcn_sched_barrier(0);
#pragma unroll
      for (int ks = 0; ks < 16; ++ks) {
        acc0 = __builtin_amdgcn_mfma_f32_16x16x32_bf16(af[ks], bfr[0][ks], acc0, 0, 0, 0);
        acc1 = __builtin_amdgcn_mfma_f32_16x16x32_bf16(af[ks], bfr[1][ks], acc1, 0, 0, 0);
      }
    }
#pragma unroll
    for (int j = 0; j < 4; ++j) {
      pre[rg * 4 + j][wv * 32 + cl]      = acc0[j];
      pre[rg * 4 + j][wv * 32 + 16 + cl] = acc1[j];
    }
    __syncthreads();

    u16* Hc = Hh + (long)t * BB * HH;
    u32 hpack = 0;
    float hv0, hv1;
#pragma unroll
    for (int q = 0; q < 2; ++q) {
      f32x4 p = *(const f32x4*)&pre[r][(2 * hp + q) * 4];
      const float pi = p[0] + bf2f((u16)xv[q * 4 + 0]);
      const float pf = p[1] + bf2f((u16)xv[q * 4 + 1]);
      const float po = p[2] + bf2f((u16)xv[q * 4 + 2]);
      const float pc = p[3] + bf2f((u16)xv[q * 4 + 3]);
      const float ig = 1.f / (1.f + __expf(-pi));
      const float fg = 1.f / (1.f + __expf(-pf));
      const float og = 1.f / (1.f + __expf(-po));
      const float ct = tanhf(pc);
      const float c  = fg * (q ? c1 : c0) + ig * ct;
      if (q) c1 = c; else c0 = c;
      const float hv = og * tanhf(c);
      if (q) hv1 = hv; else hv0 = hv;
      hpack |= (u32)f2bf(hv) << (16 * q);
    }
    st_b32_dev(&Hc[rowg * HH + hg0], hpack);     // device-scope H (MALL)
    {
      float2 dv; dv.x = hv0; dv.y = hv1;
      *(float2*)&dout[((long)t * BB + rowg) * HH + hg0] = dv;   // plain cached
      if (t == TT - 1) {
        *(float2*)&doutH[rowg * HH + hg0] = dv;
        float2 cv; cv.x = c0; cv.y = c1;
        *(float2*)&doutC[rowg * HH + hg0] = cv;
      }
    }

    // drain this wave's stores, then WG-wide arrive
    asm volatile("s_waitcnt vmcnt(0)" ::: "memory");
    __syncthreads();
    if (tid == 0 && t + 1 < t1)
      __hip_atomic_store(&flags[role * 32], (u32)(t + 1),
                         __ATOMIC_RELAXED, __HIP_MEMORY_SCOPE_AGENT);
  }

  Cst[rowg * HH + hg0]     = c0;   // plain; flushed at kernel end
  Cst[rowg * HH + hg0 + 1] = c1;
}

// ---------------- host ----------------
extern "C" void kernel_launch(void* const* d_in, const int* in_sizes, int n_in,
                              void* d_out, int out_size, void* d_ws, size_t ws_size,
                              hipStream_t stream)
{
  const float* inputs = (const float*)d_in[0];
  const float* W_xi = (const float*)d_in[1];
  const float* W_hi = (const float*)d_in[2];
  const float* b_i  = (const float*)d_in[3];
  const float* W_xf = (const float*)d_in[4];
  const float* W_hf = (const float*)d_in[5];
  const float* b_f  = (const float*)d_in[6];
  const float* W_xo = (const float*)d_in[7];
  const float* W_ho = (const float*)d_in[8];
  const float* b_o  = (const float*)d_in[9];
  const float* W_xc = (const float*)d_in[10];
  const float* W_hc = (const float*)d_in[11];
  const float* b_c  = (const float*)d_in[12];
  float* out = (float*)d_out;
  char* ws = (char*)d_ws;

  size_t off = 0;
  auto walloc = [&](size_t sz) { size_t o = off; off = (off + sz + 255) & ~(size_t)255; return o; };
  const size_t o_inbf  = walloc((size_t)TT * BB * DD * 2);   // 64 MB
  const size_t o_WxT   = walloc((size_t)NG * DD * 2);        // 2 MB
  const size_t o_WhT   = walloc((size_t)NG * HH * 2);        // 2 MB
  const size_t o_bias  = walloc((size_t)NG * 4);
  const size_t o_C     = walloc((size_t)BB * HH * 4);
  const size_t o_Hh    = walloc((size_t)TT * BB * HH * 2);   // 64 MB history
  const size_t o_flags = walloc(8192);
  const size_t o_X     = off;

  const size_t bytes_per_step = (size_t)BB * NG * 2;         // 256 KB
  long spc = (ws_size > o_X) ? (long)((ws_size - o_X) / bytes_per_step) : 0;
  if (spc > TT) spc = TT;
  spc &= ~1L;
  if (spc < 2) spc = 2;

  u16*   inbf  = (u16*)(ws + o_inbf);
  u16*   WxT   = (u16*)(ws + o_WxT);
  u16*   WhT   = (u16*)(ws + o_WhT);
  float* biasp = (float*)(ws + o_bias);
  u16*   Xbuf  = (u16*)(ws + o_X);
  u16*   Hh    = (u16*)(ws + o_Hh);
  float* Cst   = (float*)(ws + o_C);

  k_cast<<<dim3((TT * BB * DD) / 1024), dim3(256), 0, stream>>>(inputs, inbf, (long)TT * BB * DD);
  k_pack<<<dim3(DD), dim3(256), 0, stream>>>(W_xi, W_hi, b_i, W_xf, W_hf, b_f,
                                             W_xo, W_ho, b_o, W_xc, W_hc, b_c,
                                             WxT, WhT, biasp);

  float* doutH = out + (size_t)TT * BB * HH;
  float* doutC = doutH + (size_t)BB * HH;

  for (int t0 = 0; t0 < TT; t0 += (int)spc) {
    int t1 = t0 + (int)spc; if (t1 > TT) t1 = TT;
    const int rows = (t1 - t0) * BB;
    k_gemm_x<<<dim3(NG / 128, rows / 128), dim3(256), 0, stream>>>(
        inbf + (size_t)t0 * BB * DD, WxT, biasp, Xbuf);
    hipMemsetAsync(ws + o_flags, 0, 8192, stream);
    k_lstm<<<dim3(NPART), dim3(512), 0, stream>>>(
        Xbuf, WhT, Hh, Cst, out, doutH, doutC,
        (u32*)(ws + o_flags), t0, t1);
  }
}

// Round 4
// 4314.612 us; speedup vs baseline: 3.6300x; 1.4957x over previous
//
#include <hip/hip_runtime.h>
#include <hip/hip_bf16.h>
#include <stdint.h>

// LSTM (T=1024, B=64, D=512, H=512) on gfx950.
// Phase 1: X[t,b,n] = inputs @ Wx (packed, bf16 MFMA), n = h*4 + gate.
// Phase 2: batch rows are independent in the recurrence -> 8 teams of 8 WGs,
//   each team owns 8 batch rows and (when its members share an XCD) exchanges
//   H through the XCD-local coherent L2: plain stores + plain first-touch
//   loads (H history buffer = unique address per t) + agent-atomic flag polls
//   (probe L2 first -> fast for dirty-local lines). Teams are formed
//   adaptively from HW_REG_XCC_ID with a deterministic deficit-fill; any team
//   with a remote member falls back to the proven device-scope (sc1/MALL)
//   protocol. No threadfence / wbl2 anywhere.

typedef float    f32x4  __attribute__((ext_vector_type(4)));
typedef short    s16x8  __attribute__((ext_vector_type(8)));
typedef unsigned short u16;
typedef u16      u16x4  __attribute__((ext_vector_type(4)));
typedef unsigned int u32;

#define TT 1024
#define BB 64
#define DD 512
#define HH 512
#define NG 2048   // 4*HH packed gate columns: n = h*4 + g, g in {i,f,o,c}
#define NTEAM 8
#define NSLOT 8
#define NLW 128   // launched WGs for k_lstm; 64 participate

__device__ __forceinline__ u16 f2bf(float f) {
  __hip_bfloat16 h = __float2bfloat16(f);
  union { __hip_bfloat16 b; u16 u; } v; v.b = h; return v.u;
}
__device__ __forceinline__ float bf2f(u16 u) {
  union { unsigned int i; float f; } v; v.i = ((unsigned int)u) << 16; return v.f;
}
__device__ __forceinline__ float sig_fast(float x) {
  return 1.f / (1.f + __expf(-x));
}
__device__ __forceinline__ float tanh_fast(float x) {
  return 1.f - 2.f / (1.f + __expf(2.f * x));
}

__device__ __forceinline__ void gload_lds16(const u16* g, u16* l) {
  __builtin_amdgcn_global_load_lds(
      (const __attribute__((address_space(1))) unsigned int*)g,
      (__attribute__((address_space(3))) unsigned int*)l, 16, 0, 0);
}

__device__ __forceinline__ void st_plain(u32* p, u32 v) {
  asm volatile("global_store_dword %0, %1, off" :: "v"(p), "v"(v) : "memory");
}

// ---------------- setup: cast inputs fp32 -> bf16 ----------------
__global__ void k_cast(const float* __restrict__ in, u16* __restrict__ out, long n) {
  long i = ((long)blockIdx.x * blockDim.x + threadIdx.x) * 4;
  if (i >= n) return;
  const float4 v = *(const float4*)(in + i);
  u16x4 o; o.x = f2bf(v.x); o.y = f2bf(v.y); o.z = f2bf(v.z); o.w = f2bf(v.w);
  *(u16x4*)(out + i) = o;
}

// ---------------- setup: pack weights transposed + gate-interleaved ----------------
__global__ void k_pack(const float* __restrict__ Wxi, const float* __restrict__ Whi, const float* __restrict__ bi,
                       const float* __restrict__ Wxf, const float* __restrict__ Whf, const float* __restrict__ bfi,
                       const float* __restrict__ Wxo, const float* __restrict__ Who, const float* __restrict__ bo,
                       const float* __restrict__ Wxc, const float* __restrict__ Whc, const float* __restrict__ bc,
                       u16* __restrict__ WxT, u16* __restrict__ WhT, float* __restrict__ biasp)
{
  const int k = blockIdx.x;  // 0..511
  const float* Wx[4] = {Wxi, Wxf, Wxo, Wxc};
  const float* Wh[4] = {Whi, Whf, Who, Whc};
  for (int h = threadIdx.x; h < HH; h += blockDim.x) {
#pragma unroll
    for (int g = 0; g < 4; ++g) {
      const long n = h * 4 + g;
      WxT[n * DD + k] = f2bf(Wx[g][(long)k * HH + h]);
      WhT[n * HH + k] = f2bf(Wh[g][(long)k * HH + h]);
    }
  }
  if (k == 0) {
    const float* bp[4] = {bi, bfi, bo, bc};
    for (int n = threadIdx.x; n < NG; n += blockDim.x)
      biasp[n] = bp[n & 3][n >> 2];
  }
}

// ---------------- phase 1: X = A(bf16) @ WxT^T + bias, store bf16 ----------------
__global__ __launch_bounds__(256) void k_gemm_x(
    const u16* __restrict__ A, const u16* __restrict__ BT,
    const float* __restrict__ biasp, u16* __restrict__ X)
{
  __shared__ __align__(16) u16 As[128 * 64];
  __shared__ __align__(16) u16 Bs[128 * 64];
  const int tid = threadIdx.x;
  const int l = tid & 63;
  const int w = tid >> 6;
  const int wr = w >> 1, wc = w & 1;
  const long brow = (long)blockIdx.y * 128;
  const int  bcol = blockIdx.x * 128;
  const int  lr = l >> 3, lc = l & 7;
  const int  cl = l & 15, rg = l >> 4;

  f32x4 acc[4][4];
#pragma unroll
  for (int m = 0; m < 4; ++m)
#pragma unroll
    for (int n = 0; n < 4; ++n) acc[m][n] = (f32x4){0.f, 0.f, 0.f, 0.f};

  for (int k0 = 0; k0 < DD; k0 += 64) {
#pragma unroll
    for (int j = 0; j < 4; ++j) {
      const int sub = w * 4 + j;
      gload_lds16(A  + (brow + sub * 8 + lr) * DD + k0 + lc * 8, &As[sub * 512]);
      gload_lds16(BT + ((long)(bcol + sub * 8 + lr)) * DD + k0 + lc * 8, &Bs[sub * 512]);
    }
    __syncthreads();
#pragma unroll
    for (int kk = 0; kk < 2; ++kk) {
      s16x8 af[4], bfr[4];
#pragma unroll
      for (int m = 0; m < 4; ++m)
        af[m] = *(const s16x8*)&As[(wr * 64 + m * 16 + cl) * 64 + kk * 32 + rg * 8];
#pragma unroll
      for (int n = 0; n < 4; ++n)
        bfr[n] = *(const s16x8*)&Bs[(wc * 64 + n * 16 + cl) * 64 + kk * 32 + rg * 8];
#pragma unroll
      for (int m = 0; m < 4; ++m)
#pragma unroll
        for (int n = 0; n < 4; ++n)
          acc[m][n] = __builtin_amdgcn_mfma_f32_16x16x32_bf16(af[m], bfr[n], acc[m][n], 0, 0, 0);
    }
    __syncthreads();
  }
#pragma unroll
  for (int n = 0; n < 4; ++n) {
    const int col = bcol + wc * 64 + n * 16 + cl;
    const float bv = biasp[col];
#pragma unroll
    for (int m = 0; m < 4; ++m)
#pragma unroll
      for (int j = 0; j < 4; ++j) {
        const long row = brow + wr * 64 + m * 16 + rg * 4 + j;
        X[row * NG + col] = f2bf(acc[m][n][j] + bv);
      }
  }
}

// ---------------- phase 2: team-local recurrent kernel ----------------
// Team g owns batch rows [8g, 8g+8); slot s in team owns h cols [64s, 64s+64)
// (gate cols [256s, 256s+256)). Teams are independent (no cross-team sync).
__global__ __launch_bounds__(512, 2) void k_lstm(
    const u16* __restrict__ X, const u16* __restrict__ WhT,
    u16* __restrict__ Hh, float* __restrict__ Cst,
    float* __restrict__ dout, float* __restrict__ doutH, float* __restrict__ doutC,
    u32* __restrict__ ctl, u32* __restrict__ flags, int t0, int t1)
{
  __shared__ __align__(16) float pre[8][260];
  __shared__ int s_team, s_slot, s_mixed;
  const int tid = threadIdx.x;

  // ---- adaptive team formation (placement-robust, deadlock-free) ----
  if (tid == 0) {
    u32 x;
    asm volatile("s_getreg_b32 %0, hwreg(HW_REG_XCC_ID)" : "=s"(x));
    x &= 7u;
    u32 r = __hip_atomic_fetch_add(&ctl[x], 1u, __ATOMIC_RELAXED, __HIP_MEMORY_SCOPE_AGENT);
    u32 p = 0;
    if (r >= NSLOT)
      p = __hip_atomic_fetch_add(&ctl[8], 1u, __ATOMIC_RELAXED, __HIP_MEMORY_SCOPE_AGENT);
    __hip_atomic_fetch_add(&ctl[9], 1u, __ATOMIC_RELAXED, __HIP_MEMORY_SCOPE_AGENT);
    while (__hip_atomic_load(&ctl[9], __ATOMIC_RELAXED, __HIP_MEMORY_SCOPE_AGENT) < (u32)NLW)
      __builtin_amdgcn_s_sleep(4);
    u32 c[8];
#pragma unroll
    for (int i = 0; i < 8; ++i)
      c[i] = __hip_atomic_load(&ctl[i], __ATOMIC_RELAXED, __HIP_MEMORY_SCOPE_AGENT);
    int team = -1, slot = 0;
    if (r < NSLOT) { team = (int)x; slot = (int)r; }
    else {
      u32 acc = 0;
      for (int tt = 0; tt < 8; ++tt) {
        u32 have = c[tt] < NSLOT ? c[tt] : NSLOT;
        u32 miss = NSLOT - have;
        if (team < 0 && p < acc + miss) { team = tt; slot = (int)(have + (p - acc)); }
        acc += miss;
      }
    }
    s_team = team; s_slot = slot;
    s_mixed = (team >= 0 && c[team] < NSLOT) ? 1 : 0;
  }
  __syncthreads();
  const int team = s_team, slot = s_slot, mixed = s_mixed;
  if (team < 0) return;

  const int l = tid & 63, wv = tid >> 6;
  const int cl = l & 15, rg = l >> 4;
  const int gcol0 = slot * 256 + wv * 32;   // this wave's gate-col base

  // constant B fragments (registers, loaded once)
  s16x8 bfr[2][16];
#pragma unroll
  for (int nt = 0; nt < 2; ++nt)
#pragma unroll
    for (int ks = 0; ks < 16; ++ks)
      bfr[nt][ks] = *(const s16x8*)&WhT[(long)(gcol0 + nt * 16 + cl) * HH + ks * 32 + rg * 8];

  // pointwise ownership: 1 thread = (row, h)
  const int prow = tid >> 6;               // 0..7  (== wv)
  const int phl  = tid & 63;               // 0..63
  const int grow = team * 8 + prow;        // global batch row
  const int ghl  = slot * 64 + phl;        // global h

  float creg;
  if (t0 == 0) creg = 0.f; else creg = Cst[grow * HH + ghl];

  u32* myflag = &flags[(team * 8 + slot) * 32];

  for (int t = t0; t < t1; ++t) {
    const int s = t - t0;
    // X for this step (issued before the poll; read-only, no hazard)
    u16x4 xv = *(const u16x4*)&X[((long)s * BB + grow) * NG + slot * 256 + phl * 4];

    if (t > t0) {                           // all team flags >= t
      if (wv == 0) {
        const u32 tgt = (u32)t;
        u32 vv; unsigned long long b;
        do {
          vv = (l < NSLOT)
             ? __hip_atomic_load(&flags[(team * 8 + l) * 32], __ATOMIC_RELAXED, __HIP_MEMORY_SCOPE_AGENT)
             : tgt;
          b = __ballot(vv >= tgt);
        } while (b != ~0ULL);
      }
      __syncthreads();
    }

    f32x4 acc0 = (f32x4){0.f,0.f,0.f,0.f}, acc1 = (f32x4){0.f,0.f,0.f,0.f};
    if (t > 0) {
      const u16* Hp = Hh + (long)(t - 1) * BB * HH;
      s16x8 af[16];
#pragma unroll
      for (int ks = 0; ks < 16; ++ks) af[ks] = (s16x8){0,0,0,0,0,0,0,0};
      if (cl < 8) {
#pragma unroll
        for (int ks = 0; ks < 16; ++ks)
          af[ks] = *(const s16x8*)&Hp[(team * 8 + cl) * HH + ks * 32 + rg * 8];
      }
#pragma unroll
      for (int ks = 0; ks < 16; ++ks) {
        acc0 = __builtin_amdgcn_mfma_f32_16x16x32_bf16(af[ks], bfr[0][ks], acc0, 0, 0, 0);
        acc1 = __builtin_amdgcn_mfma_f32_16x16x32_bf16(af[ks], bfr[1][ks], acc1, 0, 0, 0);
      }
    }
    if (rg < 2) {                            // valid output rows 0..7
#pragma unroll
      for (int j = 0; j < 4; ++j) {
        pre[rg * 4 + j][wv * 32 + cl]      = acc0[j];
        pre[rg * 4 + j][wv * 32 + 16 + cl] = acc1[j];
      }
    }
    __syncthreads();

    // pointwise: 4 gates of one h
    f32x4 pv = *(const f32x4*)&pre[prow][phl * 4];
    const float pi = pv[0] + bf2f((u16)xv.x);
    const float pf = pv[1] + bf2f((u16)xv.y);
    const float po = pv[2] + bf2f((u16)xv.z);
    const float pc = pv[3] + bf2f((u16)xv.w);
    const float ig = sig_fast(pi);
    const float fg = sig_fast(pf);
    const float og = sig_fast(po);
    const float ct = tanh_fast(pc);
    creg = fg * creg + ig * ct;
    const float hv = og * tanh_fast(creg);
    const u16 hb = f2bf(hv);
    u16* hdst = &Hh[((long)t * BB + grow) * HH + ghl];
    if (!mixed) *hdst = hb;
    else asm volatile("global_store_short %0, %1, off sc1"
                      :: "v"(hdst), "v"((u32)hb) : "memory");

    // drain H stores, then arrive; dout goes AFTER the flag (off critical path)
    asm volatile("s_waitcnt vmcnt(0)" ::: "memory");
    __syncthreads();
    if (tid == 0) {
      if (!mixed) st_plain(myflag, (u32)(t + 1));
      else __hip_atomic_store(myflag, (u32)(t + 1),
                              __ATOMIC_RELAXED, __HIP_MEMORY_SCOPE_AGENT);
    }
    dout[((long)t * BB + grow) * HH + ghl] = hv;
    if (t == TT - 1) {
      doutH[grow * HH + ghl] = hv;
      doutC[grow * HH + ghl] = creg;
    }
  }

  Cst[grow * HH + ghl] = creg;   // plain; flushed at kernel end
}

// ---------------- host ----------------
extern "C" void kernel_launch(void* const* d_in, const int* in_sizes, int n_in,
                              void* d_out, int out_size, void* d_ws, size_t ws_size,
                              hipStream_t stream)
{
  const float* inputs = (const float*)d_in[0];
  const float* W_xi = (const float*)d_in[1];
  const float* W_hi = (const float*)d_in[2];
  const float* b_i  = (const float*)d_in[3];
  const float* W_xf = (const float*)d_in[4];
  const float* W_hf = (const float*)d_in[5];
  const float* b_f  = (const float*)d_in[6];
  const float* W_xo = (const float*)d_in[7];
  const float* W_ho = (const float*)d_in[8];
  const float* b_o  = (const float*)d_in[9];
  const float* W_xc = (const float*)d_in[10];
  const float* W_hc = (const float*)d_in[11];
  const float* b_c  = (const float*)d_in[12];
  float* out = (float*)d_out;
  char* ws = (char*)d_ws;

  size_t off = 0;
  auto walloc = [&](size_t sz) { size_t o = off; off = (off + sz + 255) & ~(size_t)255; return o; };
  const size_t o_inbf  = walloc((size_t)TT * BB * DD * 2);   // 64 MB
  const size_t o_WxT   = walloc((size_t)NG * DD * 2);        // 2 MB
  const size_t o_WhT   = walloc((size_t)NG * HH * 2);        // 2 MB
  const size_t o_bias  = walloc((size_t)NG * 4);
  const size_t o_C     = walloc((size_t)BB * HH * 4);
  const size_t o_Hh    = walloc((size_t)TT * BB * HH * 2);   // 64 MB history
  const size_t o_ctl   = walloc(256);
  const size_t o_flags = walloc(8192);
  const size_t o_X     = off;

  const size_t bytes_per_step = (size_t)BB * NG * 2;         // 256 KB
  long spc = (ws_size > o_X) ? (long)((ws_size - o_X) / bytes_per_step) : 0;
  if (spc > TT) spc = TT;
  spc &= ~1L;
  if (spc < 2) spc = 2;

  u16*   inbf  = (u16*)(ws + o_inbf);
  u16*   WxT   = (u16*)(ws + o_WxT);
  u16*   WhT   = (u16*)(ws + o_WhT);
  float* biasp = (float*)(ws + o_bias);
  u16*   Xbuf  = (u16*)(ws + o_X);
  u16*   Hh    = (u16*)(ws + o_Hh);
  float* Cst   = (float*)(ws + o_C);

  k_cast<<<dim3((TT * BB * DD) / 1024), dim3(256), 0, stream>>>(inputs, inbf, (long)TT * BB * DD);
  k_pack<<<dim3(DD), dim3(256), 0, stream>>>(W_xi, W_hi, b_i, W_xf, W_hf, b_f,
                                             W_xo, W_ho, b_o, W_xc, W_hc, b_c,
                                             WxT, WhT, biasp);

  float* doutH = out + (size_t)TT * BB * HH;
  float* doutC = doutH + (size_t)BB * HH;

  for (int t0 = 0; t0 < TT; t0 += (int)spc) {
    int t1 = t0 + (int)spc; if (t1 > TT) t1 = TT;
    const int rows = (t1 - t0) * BB;
    k_gemm_x<<<dim3(NG / 128, rows / 128), dim3(256), 0, stream>>>(
        inbf + (size_t)t0 * BB * DD, WxT, biasp, Xbuf);
    hipMemsetAsync(ws + o_ctl, 0, 256, stream);
    hipMemsetAsync(ws + o_flags, 0, 8192, stream);
    k_lstm<<<dim3(NLW), dim3(512), 0, stream>>>(
        Xbuf, WhT, Hh, Cst, out, doutH, doutC,
        (u32*)(ws + o_ctl), (u32*)(ws + o_flags), t0, t1);
  }
}